// Round 13
// baseline (296.245 us; speedup 1.0000x reference)
//
#include <hip/hip_runtime.h>
#include <hip/hip_bf16.h>
#include <cmath>

// Problem constants
#define B_   32
#define S_   512
#define E_   256
#define H_   8
#define DH_  32
#define L_   2
#define R_   4
#define NUMC_ 200
#define MAXPOS_ 512
#define MTOK (B_ * S_)          // 16384 tokens

typedef __attribute__((ext_vector_type(8))) short bf16x8_t;   // 8 bf16 = 4 VGPR
typedef __attribute__((ext_vector_type(4))) float f32x4_t;

__device__ inline ushort bfu(float a) {
    union { __hip_bfloat16 h; ushort u; } x; x.h = __float2bfloat16(a); return x.u;
}
__device__ inline uint pk2bf(float a, float b) {
    return (uint)bfu(a) | ((uint)bfu(b) << 16);
}
__device__ inline float bf2f(ushort u) {
    union { float f; uint u; } x; x.u = (uint)u << 16; return x.f;
}
__device__ inline __hip_bfloat16 f2bf(float a) { return __float2bfloat16(a); }

// ---------------------------------------------------------------------------
// Fused setup: weight convert/transpose + positional pads + embedding gather.
// blocks [0,480): weights -> wb; [480,552): pos pads; [552,4648): embed.
// Weight layout (bf16 elems):
//   [0,262144)        qcCe  [512][512]  (qcWT rows 0-255; ceT rows 256-511)
//   [262144,393216)   linWT [256][512]
//   [393216,655360)   wqkT  [2][512][256]
//   [655360,786432)   wvT   [512][256]
//   [786432,917504)   o1WT  [256][512]
//   [917504,983040)   o2WT  [256][256]
// ---------------------------------------------------------------------------
__global__ __launch_bounds__(256) void setup_k(
    const float* __restrict__ qcW, const float* __restrict__ linW,
    const float* __restrict__ Wq, const float* __restrict__ Wk,
    const float* __restrict__ Wv, const float* __restrict__ o1W,
    const float* __restrict__ o2W, const float* __restrict__ ce,
    const float* __restrict__ posk, const float* __restrict__ posv,
    const int* __restrict__ pid, const int* __restrict__ cdat,
    const float* __restrict__ qe,
    __hip_bfloat16* __restrict__ wb,
    __hip_bfloat16* __restrict__ pkPad, __hip_bfloat16* __restrict__ pvT,
    __hip_bfloat16* __restrict__ qemb, __hip_bfloat16* __restrict__ cemb)
{
    if (blockIdx.x >= 552) {
        // ---- embedding gather + concept average ----
        int tkn = (blockIdx.x - 552) * 4 + (threadIdx.x >> 6);
        int e4  = (threadIdx.x & 63) * 4;
        int p = pid[tkn];
        float4 q = *reinterpret_cast<const float4*>(qe + (size_t)p * E_ + e4);
        ushort4 qo; qo.x = bfu(q.x); qo.y = bfu(q.y); qo.z = bfu(q.z); qo.w = bfu(q.w);
        *reinterpret_cast<ushort4*>(qemb + (size_t)tkn * E_ + e4) = qo;
        const int* c = cdat + (size_t)tkn * R_;
        float4 s = make_float4(0.f, 0.f, 0.f, 0.f);
#pragma unroll
        for (int r = 0; r < R_; ++r) {
            float4 v = *reinterpret_cast<const float4*>(ce + (size_t)c[r] * E_ + e4);
            s.x += v.x; s.y += v.y; s.z += v.z; s.w += v.w;
        }
        ushort4 co; co.x = bfu(s.x * 0.25f); co.y = bfu(s.y * 0.25f);
        co.z = bfu(s.z * 0.25f); co.w = bfu(s.w * 0.25f);
        *reinterpret_cast<ushort4*>(cemb + (size_t)tkn * E_ + e4) = co;
        return;
    }
    if (blockIdx.x >= 480) {
        int t = (blockIdx.x - 480) * 256 + threadIdx.x;    // 72*256 = 18432
        {
            int row = t >> 5, d = t & 31;
            int rel = row - 32;
            float v = (rel >= 0 && rel < MAXPOS_) ? posk[(size_t)rel * DH_ + d] : 0.f;
            pkPad[t] = f2bf(v);
        }
        {
            int d = t / 576, c = t - d * 576;
            int rel = c - 31;
            float v = (rel >= 0 && rel < MAXPOS_) ? posv[(size_t)rel * DH_ + d] : 0.f;
            pvT[t] = f2bf(v);
        }
        return;
    }
    int id8 = blockIdx.x * 256 + threadIdx.x;   // 480*256 = 122880 (x8 elems)
    float v[8];
    size_t dst;
    if (id8 < 16384) {                          // qcCe rows 0-255: qcW^T
        int n = id8 & 255, k0 = (id8 >> 8) * 8;
#pragma unroll
        for (int j = 0; j < 8; ++j) v[j] = qcW[(size_t)(k0 + j) * 256 + n];
        dst = (size_t)n * 512 + k0;
    } else if (id8 < 32768) {                   // qcCe rows 256-511: ce (pad 0)
        int l = id8 - 16384; int c = l & 255, k0 = (l >> 8) * 8;
#pragma unroll
        for (int j = 0; j < 8; ++j)
            v[j] = (c < NUMC_ && k0 < 256) ? ce[(size_t)c * 256 + k0 + j] : 0.f;
        dst = 131072 + (size_t)c * 512 + k0;
    } else if (id8 < 49152) {                   // linWT [256][512]
        int l = id8 - 32768; int n = l & 255, k0 = (l >> 8) * 8;
#pragma unroll
        for (int j = 0; j < 8; ++j) v[j] = linW[(size_t)(k0 + j) * 256 + n];
        dst = 262144 + (size_t)n * 512 + k0;
    } else if (id8 < 81920) {                   // wqkT [2][512][256]
        int l = id8 - 49152; int n2 = l & 1023, k0 = (l >> 10) * 8;
        int ly = n2 >> 9, n = n2 & 511;
        const float* src = (n < 256) ? (Wq + ly * 65536 + n) : (Wk + ly * 65536 + (n - 256));
#pragma unroll
        for (int j = 0; j < 8; ++j) v[j] = src[(size_t)(k0 + j) * 256];
        dst = 393216 + (size_t)n2 * 256 + k0;
    } else if (id8 < 98304) {                   // wvT [512][256]
        int l = id8 - 81920; int n = l & 511, k0 = (l >> 9) * 8;
        const float* src = Wv + (n >> 8) * 65536 + (n & 255);
#pragma unroll
        for (int j = 0; j < 8; ++j) v[j] = src[(size_t)(k0 + j) * 256];
        dst = 655360 + (size_t)n * 256 + k0;
    } else if (id8 < 114688) {                  // o1WT [256][512]
        int l = id8 - 98304; int n = l & 255, k0 = (l >> 8) * 8;
#pragma unroll
        for (int j = 0; j < 8; ++j) v[j] = o1W[(size_t)(k0 + j) * 256 + n];
        dst = 786432 + (size_t)n * 512 + k0;
    } else {                                    // o2WT [256][256]
        int l = id8 - 114688; int n = l & 255, k0 = (l >> 8) * 8;
#pragma unroll
        for (int j = 0; j < 8; ++j) v[j] = o2W[(size_t)(k0 + j) * 256 + n];
        dst = 917504 + (size_t)n * 256 + k0;
    }
    union { ushort u[8]; uint4 q; } pk;
#pragma unroll
    for (int j = 0; j < 8; ++j) pk.u[j] = bfu(v[j]);
    *reinterpret_cast<uint4*>(wb + dst) = pk.q;
}

// ---------------------------------------------------------------------------
// bf16 MFMA GEMM body (device fn). M=16384, block 64x128, 4 waves of 32x64.
// AMODE: 0 plain (stride K) | 1 concat [A0|A1] | 2 gated select
// EPI: 0 none | 1 relu | 2 sigmoid
// OMODE: 0 f32 [M][Nstride] | 1 QK attn split | 2 V^T split 2 layers
//        | 3 bf16 [M][256] | 4 merged query(bf16,n<256)+sim(f32 sigmoid,n>=256)
// ---------------------------------------------------------------------------
template<int AMODE, int EPI, int OMODE, int K, int NB>
__device__ __forceinline__ void gemm_body(
    const __hip_bfloat16* __restrict__ A0, const __hip_bfloat16* __restrict__ A1,
    const int* __restrict__ lbl,
    const __hip_bfloat16* __restrict__ BT,
    const float* __restrict__ bias, const float* __restrict__ bias2,
    void* __restrict__ C0, void* __restrict__ C1, int Nstride, int did)
{
    const int lane = threadIdx.x & 63, w = threadIdx.x >> 6;
    const int col = lane & 15, rg = lane >> 4;
    const int wr = w >> 1, wc = w & 1;
    int bm, bn;
    if (NB == 512) {
        int swz = (did & 7) * 128 + (did >> 3);
        bm = (swz >> 2) * 64; bn = (swz & 3) * 128;
    } else {
        int swz = (did & 7) * 64 + (did >> 3);
        bm = (swz >> 1) * 64; bn = (swz & 1) * 128;
    }
    const f32x4_t z4 = {0.f, 0.f, 0.f, 0.f};
    f32x4_t acc[2][4] = {{z4, z4, z4, z4}, {z4, z4, z4, z4}};
    const bf16x8_t z8 = {0, 0, 0, 0, 0, 0, 0, 0};

    int rowA[2];
    rowA[0] = bm + wr * 32 + col;
    rowA[1] = bm + wr * 32 + 16 + col;
    int lblv[2] = {0, 0};
    if (AMODE == 2) { lblv[0] = lbl[rowA[0]]; lblv[1] = lbl[rowA[1]]; }
    const int nb0 = bn + wc * 64;

    auto load_step = [&](int s, bf16x8_t (&af)[2], bf16x8_t (&bfr)[4]) {
        const int kk = s * 32 + 8 * rg;
#pragma unroll
        for (int mt = 0; mt < 2; ++mt) {
            if (AMODE == 0) {
                af[mt] = *reinterpret_cast<const bf16x8_t*>(A0 + (size_t)rowA[mt] * K + kk);
            } else if (AMODE == 1) {
                const __hip_bfloat16* p = (kk < 256) ? (A0 + (size_t)rowA[mt] * 256 + kk)
                                                     : (A1 + (size_t)rowA[mt] * 256 + (kk - 256));
                af[mt] = *reinterpret_cast<const bf16x8_t*>(p);
            } else {
                bf16x8_t a = *reinterpret_cast<const bf16x8_t*>(A0 + (size_t)rowA[mt] * 256 + (kk & 255));
                bool first = (kk < 256);
                af[mt] = ((lblv[mt] != 0) == first) ? a : z8;
            }
        }
#pragma unroll
        for (int nt = 0; nt < 4; ++nt)
            bfr[nt] = *reinterpret_cast<const bf16x8_t*>(BT + (size_t)(nb0 + nt * 16 + col) * K + kk);
    };

    constexpr int NS = K / 32;
    bf16x8_t afb[2][2], bfb[2][4];
    load_step(0, afb[0], bfb[0]);
#pragma unroll
    for (int s = 0; s < NS; ++s) {
        if (s + 1 < NS) load_step(s + 1, afb[(s + 1) & 1], bfb[(s + 1) & 1]);
#pragma unroll
        for (int mt = 0; mt < 2; ++mt)
#pragma unroll
        for (int nt = 0; nt < 4; ++nt)
            acc[mt][nt] = __builtin_amdgcn_mfma_f32_16x16x32_bf16(afb[s & 1][mt], bfb[s & 1][nt], acc[mt][nt], 0, 0, 0);
    }

#pragma unroll
    for (int mt = 0; mt < 2; ++mt)
#pragma unroll
    for (int nt = 0; nt < 4; ++nt) {
        const int n = nb0 + nt * 16 + col;
        const int mb = bm + wr * 32 + mt * 16 + 4 * rg;
        float bs = 0.f;
        if (OMODE == 4) bs = (n < 256 && bias) ? bias[n] : 0.f;
        else if (bias) bs = (NB == 512 && n >= 256) ? bias2[n - 256] : bias[n];
        float xv[4];
#pragma unroll
        for (int r = 0; r < 4; ++r) {
            float x = acc[mt][nt][r] + bs;
            if (EPI == 1) x = fmaxf(x, 0.f);
            else if (EPI == 2) x = 1.f / (1.f + expf(-x));
            if (OMODE == 4 && n >= 256) x = 1.f / (1.f + expf(-x));
            xv[r] = x;
        }
        if (OMODE == 0) {
            if (n < Nstride) {
                float* C = (float*)C0;
#pragma unroll
                for (int r = 0; r < 4; ++r)
                    C[(size_t)(mb + r) * Nstride + n] = xv[r];
            }
        } else if (OMODE == 3) {
            __hip_bfloat16* Cb = (__hip_bfloat16*)C0;
#pragma unroll
            for (int r = 0; r < 4; ++r)
                Cb[(size_t)(mb + r) * 256 + n] = f2bf(xv[r]);
        } else if (OMODE == 4) {
            if (n < 256) {
                __hip_bfloat16* Cb = (__hip_bfloat16*)C0;
#pragma unroll
                for (int r = 0; r < 4; ++r)
                    Cb[(size_t)(mb + r) * 256 + n] = f2bf(xv[r]);
            } else if (n - 256 < NUMC_) {
                float* S = (float*)C1;
#pragma unroll
                for (int r = 0; r < 4; ++r)
                    S[(size_t)(mb + r) * NUMC_ + (n - 256)] = xv[r];
            }
        } else if (OMODE == 1) {
            __hip_bfloat16* dst = (n < 256) ? (__hip_bfloat16*)C0 : (__hip_bfloat16*)C1;
            const int nn = n & 255, hh = nn >> 5, d = nn & 31;
#pragma unroll
            for (int r = 0; r < 4; ++r) {
                int m = mb + r;
                int bh = (m >> 9) * 8 + hh;
                dst[((size_t)bh * 512 + (m & 511)) * 32 + d] = f2bf(xv[r]);
            }
        } else {   // OMODE 2: V^T, two layers
            __hip_bfloat16* dst = (n < 256) ? (__hip_bfloat16*)C0 : (__hip_bfloat16*)C1;
            const int nn = n & 255, hh = nn >> 5, d = nn & 31;
            const int bh = (mb >> 9) * 8 + hh;
            ushort4 pk;
            pk.x = bfu(xv[0]); pk.y = bfu(xv[1]); pk.z = bfu(xv[2]); pk.w = bfu(xv[3]);
            *reinterpret_cast<ushort4*>(dst + ((size_t)bh * 32 + d) * 512 + (mb & 511)) = pk;
        }
    }
}

template<int AMODE, int EPI, int OMODE, int K, int NB>
__global__ __launch_bounds__(256) void gemm_bf_k(
    const __hip_bfloat16* __restrict__ A0, const __hip_bfloat16* __restrict__ A1,
    const int* __restrict__ lbl,
    const __hip_bfloat16* __restrict__ BT,
    const float* __restrict__ bias, const float* __restrict__ bias2,
    void* __restrict__ C0, void* __restrict__ C1, int Nstride)
{
    gemm_body<AMODE, EPI, OMODE, K, NB>(A0, A1, lbl, BT, bias, bias2, C0, C1,
                                        Nstride, blockIdx.y * gridDim.x + blockIdx.x);
}

// ---------------------------------------------------------------------------
// Fused independent projections: z=0 -> QK layer-0 (A=query), z=1 -> V both
// layers (A=inter). 2048 blocks co-resident (8/CU) instead of 2x1024 serial.
// ---------------------------------------------------------------------------
__global__ __launch_bounds__(256) void qkv0_k(
    const __hip_bfloat16* __restrict__ query, const __hip_bfloat16* __restrict__ inter,
    const __hip_bfloat16* __restrict__ wqkT, const __hip_bfloat16* __restrict__ wvT,
    const float* __restrict__ bq, const float* __restrict__ bk,
    const float* __restrict__ bv,
    __hip_bfloat16* __restrict__ qbuf, __hip_bfloat16* __restrict__ kbuf,
    __hip_bfloat16* __restrict__ v0, __hip_bfloat16* __restrict__ v1)
{
    int did = blockIdx.y * 4 + blockIdx.x;
    if (blockIdx.z == 0)
        gemm_body<0, 0, 1, 256, 512>(query, nullptr, nullptr, wqkT, bq, bk, qbuf, kbuf, 0, did);
    else
        gemm_body<0, 0, 2, 256, 512>(inter, nullptr, nullptr, wvT, bv, bv + 256, v0, v1, 0, did);
}

// ---------------------------------------------------------------------------
// Fused head: pred[m] = sigmoid(relu(relu([outp|query]@o1W+b1)@o2W+b2).w3+b3).
// 32 rows/block (512 blocks, 2/CU). 4 waves: 2 row-halves x 2 col-halves,
// wave tile 16x128. h1 staged in LDS [32][264]ush. Register prefetch.
// ---------------------------------------------------------------------------
#define HST 264
__global__ __launch_bounds__(256) void head_k(
    const __hip_bfloat16* __restrict__ A0, const __hip_bfloat16* __restrict__ A1,
    const __hip_bfloat16* __restrict__ o1WT, const float* __restrict__ b1,
    const __hip_bfloat16* __restrict__ o2WT, const float* __restrict__ b2,
    const float* __restrict__ w3, const float* __restrict__ b3,
    float* __restrict__ pred)
{
    __shared__ __align__(16) ushort ldsH[32 * HST];   // 16896 B
    __shared__ float sl[2][32];
    const int lane = threadIdx.x & 63, w = threadIdx.x >> 6;
    const int col = lane & 15, rg = lane >> 4;
    const int wrh = w >> 1, wc = w & 1;
    const int bm = blockIdx.x * 32;
    const int nb0 = wc * 128;
    const f32x4_t z4 = {0.f, 0.f, 0.f, 0.f};

    const int rowA = bm + wrh * 16 + col;

    // ---- stage 1: h1 = relu([outp|query] @ o1WT + b1), wave tile 16x128 ----
    {
        f32x4_t acc[8];
#pragma unroll
        for (int nt = 0; nt < 8; ++nt) acc[nt] = z4;

        auto load1 = [&](int s, bf16x8_t& af, bf16x8_t (&bfr)[8]) {
            const int kk = s * 32 + 8 * rg;
            const __hip_bfloat16* p = (kk < 256) ? (A0 + (size_t)rowA * 256 + kk)
                                                 : (A1 + (size_t)rowA * 256 + (kk - 256));
            af = *reinterpret_cast<const bf16x8_t*>(p);
#pragma unroll
            for (int nt = 0; nt < 8; ++nt)
                bfr[nt] = *reinterpret_cast<const bf16x8_t*>(o1WT + (size_t)(nb0 + nt * 16 + col) * 512 + kk);
        };
        bf16x8_t afb[2], bfb[2][8];
        load1(0, afb[0], bfb[0]);
#pragma unroll
        for (int s = 0; s < 16; ++s) {
            if (s + 1 < 16) load1(s + 1, afb[(s + 1) & 1], bfb[(s + 1) & 1]);
#pragma unroll
            for (int nt = 0; nt < 8; ++nt)
                acc[nt] = __builtin_amdgcn_mfma_f32_16x16x32_bf16(afb[s & 1], bfb[s & 1][nt], acc[nt], 0, 0, 0);
        }
#pragma unroll
        for (int nt = 0; nt < 8; ++nt) {
            const int n = nb0 + nt * 16 + col;
            const float bs = b1[n];
            const int rb = wrh * 16 + 4 * rg;
#pragma unroll
            for (int r = 0; r < 4; ++r)
                ldsH[(rb + r) * HST + n] = bfu(fmaxf(acc[nt][r] + bs, 0.f));
        }
    }
    __syncthreads();

    // ---- stage 2: h2 = relu(h1 @ o2WT + b2); pr = h2 . w3 ----
    {
        f32x4_t acc[8];
#pragma unroll
        for (int nt = 0; nt < 8; ++nt) acc[nt] = z4;

        auto load2 = [&](int s, bf16x8_t& af, bf16x8_t (&bfr)[8]) {
            const int kk = s * 32 + 8 * rg;
            af = *reinterpret_cast<const bf16x8_t*>(&ldsH[(wrh * 16 + col) * HST + kk]);
#pragma unroll
            for (int nt = 0; nt < 8; ++nt)
                bfr[nt] = *reinterpret_cast<const bf16x8_t*>(o2WT + (size_t)(nb0 + nt * 16 + col) * 256 + kk);
        };
        bf16x8_t afb[2], bfb[2][8];
        load2(0, afb[0], bfb[0]);
#pragma unroll
        for (int s = 0; s < 8; ++s) {
            if (s + 1 < 8) load2(s + 1, afb[(s + 1) & 1], bfb[(s + 1) & 1]);
#pragma unroll
            for (int nt = 0; nt < 8; ++nt)
                acc[nt] = __builtin_amdgcn_mfma_f32_16x16x32_bf16(afb[s & 1], bfb[s & 1][nt], acc[nt], 0, 0, 0);
        }

        float pr[4] = {};
#pragma unroll
        for (int nt = 0; nt < 8; ++nt) {
            const int n = nb0 + nt * 16 + col;
            float bs = b2[n], wv = w3[n];
#pragma unroll
            for (int r = 0; r < 4; ++r)
                pr[r] += fmaxf(acc[nt][r] + bs, 0.f) * wv;
        }
#pragma unroll
        for (int r = 0; r < 4; ++r) {
            float v = pr[r];
            v += __shfl_xor(v, 1); v += __shfl_xor(v, 2);
            v += __shfl_xor(v, 4); v += __shfl_xor(v, 8);
            if (col == 0) sl[wc][wrh * 16 + 4 * rg + r] = v;
        }
    }
    __syncthreads();
    if (threadIdx.x < 32) {
        float s = sl[0][threadIdx.x] + sl[1][threadIdx.x] + b3[0];
        pred[bm + threadIdx.x] = 1.f / (1.f + expf(-s));
    }
}

// ---------------------------------------------------------------------------
// Relative attention, bf16 MFMA, no-max softmax. ONE WAVE per workgroup,
// BAND-PAIRED: block = bands (p, 15-p) executed sequentially -> every block
// does exactly 17 tiles (uniform load). Grid (256 bh, 8 pairs) = 2048 blocks.
// LDS 9216 B, no syncs. exp via raw v_exp_f32 (scale prefolded). (r10-12 winner)
// ---------------------------------------------------------------------------
#define QPST 36
template<int ADDREL>
__global__ __launch_bounds__(64) void attn1w_k(
    const __hip_bfloat16* __restrict__ Qbf, const __hip_bfloat16* __restrict__ Kbf,
    const __hip_bfloat16* __restrict__ Vt,  const __hip_bfloat16* __restrict__ pkPad,
    const __hip_bfloat16* __restrict__ pvT, __hip_bfloat16* __restrict__ outp)
{
    __shared__ __align__(16) ushort ldsA[64 * QPST];   // QP_T [64][36] / Ps [32][32]
    __shared__ __align__(16) ushort ldsP[2304];        // Prs  [32][72]

    const int lane = threadIdx.x;
    const int col = lane & 15, rg = lane >> 4;
    const int bh = blockIdx.x, b = bh >> 3, h = bh & 7;
    const int p = blockIdx.y;                  // pair index 0..7

    const __hip_bfloat16* Qb = Qbf + (size_t)bh * 512 * 32;
    const __hip_bfloat16* Kb = Kbf + (size_t)bh * 512 * 32;
    const __hip_bfloat16* Vb = Vt  + (size_t)bh * 32 * 512;

    const f32x4_t z4 = {0.f, 0.f, 0.f, 0.f};
    const float rscale2 = 0.17677669529663687f * 1.4426950408889634f;

    for (int ph = 0; ph < 2; ++ph) {
        const int band = ph ? p : (15 - p);    // long band first
        const int i0 = band * 32;
        const int nT = band + 1;

        // zero Prs (window [ii,ii+31] per row is tile-invariant; rest must be 0)
        {
            uint4 zz = make_uint4(0u, 0u, 0u, 0u);
            uint4* pz = reinterpret_cast<uint4*>(ldsP);
#pragma unroll
            for (int t = 0; t < 5; ++t) {
                int idx = lane + 64 * t;
                if (idx < 288) pz[idx] = zz;
            }
        }

        bf16x8_t qf[2];
        qf[0] = *reinterpret_cast<const bf16x8_t*>(Qb + (size_t)(i0 + col) * 32 + 8 * rg);
        qf[1] = *reinterpret_cast<const bf16x8_t*>(Qb + (size_t)(i0 + 16 + col) * 32 + 8 * rg);

        f32x4_t o[2][2] = {{z4, z4}, {z4, z4}};
        float lrow[2][4] = {};

        for (int t = 0; t < nT; ++t) {
            const int j0 = t * 32;
            bf16x8_t kf0 = *reinterpret_cast<const bf16x8_t*>(Kb + (size_t)(j0 + col) * 32 + 8 * rg);
            bf16x8_t kf1 = *reinterpret_cast<const bf16x8_t*>(Kb + (size_t)(j0 + 16 + col) * 32 + 8 * rg);
            const int prow0 = i0 - j0 + 1;
            bf16x8_t pkf[4];
#pragma unroll
            for (int rt = 0; rt < 4; ++rt)
                pkf[rt] = *reinterpret_cast<const bf16x8_t*>(
                    pkPad + (size_t)(prow0 + rt * 16 + col) * 32 + 8 * rg);

            __builtin_amdgcn_s_setprio(1);
            f32x4_t sA[2][2];
            sA[0][0] = __builtin_amdgcn_mfma_f32_16x16x32_bf16(qf[0], kf0, z4, 0, 0, 0);
            sA[0][1] = __builtin_amdgcn_mfma_f32_16x16x32_bf16(qf[0], kf1, z4, 0, 0, 0);
            sA[1][0] = __builtin_amdgcn_mfma_f32_16x16x32_bf16(qf[1], kf0, z4, 0, 0, 0);
            sA[1][1] = __builtin_amdgcn_mfma_f32_16x16x32_bf16(qf[1], kf1, z4, 0, 0, 0);
            f32x4_t qp0[4], qp1[4];
#pragma unroll
            for (int rt = 0; rt < 4; ++rt) {
                qp0[rt] = __builtin_amdgcn_mfma_f32_16x16x32_bf16(qf[0], pkf[rt], z4, 0, 0, 0);
                qp1[rt] = __builtin_amdgcn_mfma_f32_16x16x32_bf16(qf[1], pkf[rt], z4, 0, 0, 0);
            }
            __builtin_amdgcn_s_setprio(0);

            // QP transposed store: ldsA[x][ii], x = local rel 0..63, stride QPST
#pragma unroll
            for (int rt = 0; rt < 4; ++rt) {
                int xo = (rt * 16 + col) * QPST;
                uint2 wv;
                wv.x = pk2bf(qp0[rt][0], qp0[rt][1]);
                wv.y = pk2bf(qp0[rt][2], qp0[rt][3]);
                *reinterpret_cast<uint2*>(&ldsA[xo + 4 * rg]) = wv;
                wv.x = pk2bf(qp1[rt][0], qp1[rt][1]);
                wv.y = pk2bf(qp1[rt][2], qp1[rt][3]);
                *reinterpret_cast<uint2*>(&ldsA[xo + 16 + 4 * rg]) = wv;
            }

            // scores: gather QP diagonal, exp2 (scale prefolded), row sums
            const bool diag = (j0 == i0);
            float ev[2][2][4];
#pragma unroll
            for (int mt = 0; mt < 2; ++mt)
#pragma unroll
            for (int r = 0; r < 4; ++r) {
                const int ii = mt * 16 + 4 * rg + r;
#pragma unroll
                for (int nt = 0; nt < 2; ++nt) {
                    const int jj = nt * 16 + col;
                    float qpv = bf2f(ldsA[(ii - jj + 31) * QPST + ii]);
                    float sc = (sA[mt][nt][r] + qpv) * rscale2;
                    float e = __builtin_amdgcn_exp2f(sc);
                    if (diag && jj >= ii) e = 0.f;
                    ev[mt][nt][r] = e;
                }
                lrow[mt][r] += ev[mt][0][r] + ev[mt][1][r];
            }

            // P stores: dense swizzled Ps (reuses ldsA) + scattered Prs
#pragma unroll
            for (int mt = 0; mt < 2; ++mt)
#pragma unroll
            for (int nt = 0; nt < 2; ++nt)
#pragma unroll
            for (int r = 0; r < 4; ++r) {
                const int ii = mt * 16 + 4 * rg + r;
                const int jj = nt * 16 + col;
                ushort pe = bfu(ev[mt][nt][r]);
                ldsA[ii * 32 + (jj ^ ((ii & 3) << 3))] = pe;
                ldsP[ii * 72 + (ii - jj + 31)] = pe;
            }

            // O += P V  +  Pr posv
            bf16x8_t pa0 = *reinterpret_cast<const bf16x8_t*>(&ldsA[col * 32 + (8 * rg ^ ((col & 3) << 3))]);
            bf16x8_t pa1 = *reinterpret_cast<const bf16x8_t*>(&ldsA[(16 + col) * 32 + (8 * rg ^ ((col & 3) << 3))]);
            bf16x8_t vf0 = *reinterpret_cast<const bf16x8_t*>(Vb + (size_t)col * 512 + j0 + 8 * rg);
            bf16x8_t vf1 = *reinterpret_cast<const bf16x8_t*>(Vb + (size_t)(16 + col) * 512 + j0 + 8 * rg);
            bf16x8_t pr0[2], pr1[2], pv0[2], pv1[2];
#pragma unroll
            for (int ks = 0; ks < 2; ++ks) {
                pr0[ks] = *reinterpret_cast<const bf16x8_t*>(&ldsP[col * 72 + ks * 32 + 8 * rg]);
                pr1[ks] = *reinterpret_cast<const bf16x8_t*>(&ldsP[(16 + col) * 72 + ks * 32 + 8 * rg]);
                const __hip_bfloat16* pvb = pvT + (i0 - j0) + ks * 32 + 8 * rg;
                pv0[ks] = *reinterpret_cast<const bf16x8_t*>(pvb + (size_t)col * 576);
                pv1[ks] = *reinterpret_cast<const bf16x8_t*>(pvb + (size_t)(16 + col) * 576);
            }
            __builtin_amdgcn_s_setprio(1);
            o[0][0] = __builtin_amdgcn_mfma_f32_16x16x32_bf16(pa0, vf0, o[0][0], 0, 0, 0);
            o[0][1] = __builtin_amdgcn_mfma_f32_16x16x32_bf16(pa0, vf1, o[0][1], 0, 0, 0);
            o[1][0] = __builtin_amdgcn_mfma_f32_16x16x32_bf16(pa1, vf0, o[1][0], 0, 0, 0);
            o[1][1] = __builtin_amdgcn_mfma_f32_16x16x32_bf16(pa1, vf1, o[1][1], 0, 0, 0);
#pragma unroll
            for (int ks = 0; ks < 2; ++ks) {
                o[0][0] = __builtin_amdgcn_mfma_f32_16x16x32_bf16(pr0[ks], pv0[ks], o[0][0], 0, 0, 0);
                o[0][1] = __builtin_amdgcn_mfma_f32_16x16x32_bf16(pr0[ks], pv1[ks], o[0][1], 0, 0, 0);
                o[1][0] = __builtin_amdgcn_mfma_f32_16x16x32_bf16(pr1[ks], pv0[ks], o[1][0], 0, 0, 0);
                o[1][1] = __builtin_amdgcn_mfma_f32_16x16x32_bf16(pr1[ks], pv1[ks], o[1][1], 0, 0, 0);
            }
            __builtin_amdgcn_s_setprio(0);
        }

        // epilogue: reduce row sums, divide, (fused add-relu), bf16 store
#pragma unroll
        for (int mt = 0; mt < 2; ++mt)
#pragma unroll
        for (int r = 0; r < 4; ++r) {
            float ls = lrow[mt][r];
            ls += __shfl_xor(ls, 1); ls += __shfl_xor(ls, 2);
            ls += __shfl_xor(ls, 4); ls += __shfl_xor(ls, 8);
            const int i = i0 + mt * 16 + 4 * rg + r;
            float inv = (i == 0) ? 0.f : 1.0f / ls;
            __hip_bfloat16* orow = outp + (size_t)(b * 512 + i) * 256 + h * 32;
            float v0 = o[mt][0][r] * inv;
            float v1 = o[mt][1][r] * inv;
            if (ADDREL) {
                v0 = bf2f(*(ushort*)&orow[col])      + fmaxf(v0, 0.f);
                v1 = bf2f(*(ushort*)&orow[16 + col]) + fmaxf(v1, 0.f);
            }
            orow[col]      = f2bf(v0);
            orow[16 + col] = f2bf(v1);
        }
    }
}

// ---------------------------------------------------------------------------
extern "C" void kernel_launch(void* const* d_in, const int* in_sizes, int n_in,
                              void* d_out, int out_size, void* d_ws, size_t ws_size,
                              hipStream_t stream)
{
    const int*   pid        = (const int*)d_in[0];
    const int*   cdat       = (const int*)d_in[1];
    const int*   target     = (const int*)d_in[2];
    const float* que_emb    = (const float*)d_in[3];
    const float* concept_emb= (const float*)d_in[4];
    const float* posk       = (const float*)d_in[5];
    const float* posv       = (const float*)d_in[6];
    const float* qcW        = (const float*)d_in[7];
    const float* qcb        = (const float*)d_in[8];
    const float* linW       = (const float*)d_in[9];
    const float* linb       = (const float*)d_in[10];
    const float* Wq         = (const float*)d_in[11];
    const float* bq         = (const float*)d_in[12];
    const float* Wk         = (const float*)d_in[13];
    const float* bk         = (const float*)d_in[14];
    const float* Wv         = (const float*)d_in[15];
    const float* bv         = (const float*)d_in[16];
    const float* o1W        = (const float*)d_in[17];
    const float* o1b        = (const float*)d_in[18];
    const float* o2W        = (const float*)d_in[19];
    const float* o2b        = (const float*)d_in[20];
    const float* o3W        = (const float*)d_in[21];
    const float* o3b        = (const float*)d_in[22];

    float* out  = (float*)d_out;
    float* pred = out;                       // [B,S]
    float* sim  = out + MTOK;                // [B,S,200]

    __hip_bfloat16* wsb = (__hip_bfloat16*)d_ws;
    const size_t HB = (size_t)MTOK * E_;     // 4 Mi bf16 elems = 8 MB
    __hip_bfloat16* qemb  = wsb + 0 * HB;
    __hip_bfloat16* cemb  = wsb + 1 * HB;
    __hip_bfloat16* query = wsb + 2 * HB;
    __hip_bfloat16* inter = wsb + 3 * HB;
    __hip_bfloat16* qbuf  = wsb + 4 * HB;
    __hip_bfloat16* kbuf  = wsb + 5 * HB;
    __hip_bfloat16* v0    = wsb + 6 * HB;
    __hip_bfloat16* v1    = wsb + 7 * HB;
    __hip_bfloat16* outp  = wsb + 8 * HB;
    __hip_bfloat16* wb    = wsb + 9 * HB;    // 983040 weights + pads
    __hip_bfloat16* qcCe  = wb;              // [512][512] (qcWT ; ceT padded)
    __hip_bfloat16* linWT = wb + 262144;
    __hip_bfloat16* wqkT  = wb + 393216;     // [2][512][256]
    __hip_bfloat16* wvT   = wb + 655360;     // [512][256]
    __hip_bfloat16* o1WT  = wb + 786432;
    __hip_bfloat16* o2WT  = wb + 917504;
    __hip_bfloat16* pkPad = wb + 983040;     // 576*32
    __hip_bfloat16* pvT   = pkPad + 18432;   // 32*576

    dim3 blk(256);
    dim3 g256(2, 256);           // NB=256 GEMMs (512 blocks, 64x128 tiles)
    dim3 g512(4, 256);           // NB=512 GEMMs (1024 blocks)
    dim3 gqkv(4, 256, 2);        // fused QK0+V (2048 blocks)
    dim3 gattn(B_ * H_, 8);      // (bh, band pair) — one wave, 17 tiles each
    dim3 blk64(64);

    // fused setup: weights + pads + embedding
    setup_k<<<4648, blk, 0, stream>>>(qcW, linW, Wq, Wk, Wv, o1W, o2W, concept_emb,
                                      posk, posv, pid, cdat, que_emb,
                                      wb, pkPad, pvT, qemb, cemb);

    // merged: query (n<256) = [qemb|cemb]@qcW+qcb ; sim (n>=256) = sigmoid(qemb@ce^T)
    gemm_bf_k<1, 0, 4, 512, 512><<<g512, blk, 0, stream>>>(qemb, cemb, nullptr, qcCe, qcb, nullptr, query, sim, 0);
    // inter = relu(gated(query) @ lin_W + lin_b)         -> bf16 [M][256]
    gemm_bf_k<2, 1, 3, 512, 256><<<g256, blk, 0, stream>>>(query, nullptr, target, linWT, linb, nullptr, inter, nullptr, 256);

    // fused independent projections: QK layer-0 + V both layers
    qkv0_k<<<gqkv, blk, 0, stream>>>(query, inter, wqkT, wvT, bq, bk, bv,
                                     qbuf, kbuf, v0, v1);
    attn1w_k<0><<<gattn, blk64, 0, stream>>>(qbuf, kbuf, v0, pkPad, pvT, outp);

    // ---- layer 1: q,k from outp; fused outp += relu(res) ----
    gemm_bf_k<0, 0, 1, 256, 512><<<g512, blk, 0, stream>>>(outp, nullptr, nullptr, wqkT + 131072, bq + 256, bk + 256, qbuf, kbuf, 0);
    attn1w_k<1><<<gattn, blk64, 0, stream>>>(qbuf, kbuf, v1, pkPad, pvT, outp);

    // fused head: o1 -> o2 -> o3 -> sigmoid (512 blocks of 32 rows)
    head_k<<<512, blk, 0, stream>>>(outp, query, o1WT, o1b, o2WT, o2b, o3W, o3b, pred);
}

// Round 14
// 281.158 us; speedup vs baseline: 1.0537x; 1.0537x over previous
//
#include <hip/hip_runtime.h>
#include <hip/hip_bf16.h>
#include <cmath>

// Problem constants
#define B_   32
#define S_   512
#define E_   256
#define H_   8
#define DH_  32
#define L_   2
#define R_   4
#define NUMC_ 200
#define MAXPOS_ 512
#define MTOK (B_ * S_)          // 16384 tokens

typedef __attribute__((ext_vector_type(8))) short bf16x8_t;   // 8 bf16 = 4 VGPR
typedef __attribute__((ext_vector_type(4))) float f32x4_t;

__device__ inline ushort bfu(float a) {
    union { __hip_bfloat16 h; ushort u; } x; x.h = __float2bfloat16(a); return x.u;
}
__device__ inline uint pk2bf(float a, float b) {
    return (uint)bfu(a) | ((uint)bfu(b) << 16);
}
__device__ inline float bf2f(ushort u) {
    union { float f; uint u; } x; x.u = (uint)u << 16; return x.f;
}
__device__ inline __hip_bfloat16 f2bf(float a) { return __float2bfloat16(a); }

// ---------------------------------------------------------------------------
// Weight convert/transpose to bf16 [N][K] + positional pads (one-shot).
// Layout (bf16 elems):
//   [0,262144)        qcCe  [512][512]  (qcWT rows 0-255; ceT rows 256-511)
//   [262144,393216)   linWT [256][512]
//   [393216,655360)   wqkT  [2][512][256]
//   [655360,786432)   wvT   [512][256]
//   [786432,917504)   o1WT  [256][512]
//   [917504,983040)   o2WT  [256][256]
// blocks 480..551: posk/posv pads at wb+983040.
// ---------------------------------------------------------------------------
__global__ __launch_bounds__(256) void wcvt_k(
    const float* __restrict__ qcW, const float* __restrict__ linW,
    const float* __restrict__ Wq, const float* __restrict__ Wk,
    const float* __restrict__ Wv, const float* __restrict__ o1W,
    const float* __restrict__ o2W, const float* __restrict__ ce,
    const float* __restrict__ posk, const float* __restrict__ posv,
    __hip_bfloat16* __restrict__ wb,
    __hip_bfloat16* __restrict__ pkPad, __hip_bfloat16* __restrict__ pvT)
{
    if (blockIdx.x >= 480) {
        int t = (blockIdx.x - 480) * 256 + threadIdx.x;    // 72*256 = 18432
        {
            int row = t >> 5, d = t & 31;
            int rel = row - 32;
            float v = (rel >= 0 && rel < MAXPOS_) ? posk[(size_t)rel * DH_ + d] : 0.f;
            pkPad[t] = f2bf(v);
        }
        {
            int d = t / 576, c = t - d * 576;
            int rel = c - 31;
            float v = (rel >= 0 && rel < MAXPOS_) ? posv[(size_t)rel * DH_ + d] : 0.f;
            pvT[t] = f2bf(v);
        }
        return;
    }
    int id8 = blockIdx.x * 256 + threadIdx.x;   // 480*256 = 122880 (x8 elems)
    float v[8];
    size_t dst;
    if (id8 < 16384) {                          // qcCe rows 0-255: qcW^T
        int n = id8 & 255, k0 = (id8 >> 8) * 8;
#pragma unroll
        for (int j = 0; j < 8; ++j) v[j] = qcW[(size_t)(k0 + j) * 256 + n];
        dst = (size_t)n * 512 + k0;
    } else if (id8 < 32768) {                   // qcCe rows 256-511: ce (pad 0)
        int l = id8 - 16384; int c = l & 255, k0 = (l >> 8) * 8;
#pragma unroll
        for (int j = 0; j < 8; ++j)
            v[j] = (c < NUMC_ && k0 < 256) ? ce[(size_t)c * 256 + k0 + j] : 0.f;
        dst = 131072 + (size_t)c * 512 + k0;
    } else if (id8 < 49152) {                   // linWT [256][512]
        int l = id8 - 32768; int n = l & 255, k0 = (l >> 8) * 8;
#pragma unroll
        for (int j = 0; j < 8; ++j) v[j] = linW[(size_t)(k0 + j) * 256 + n];
        dst = 262144 + (size_t)n * 512 + k0;
    } else if (id8 < 81920) {                   // wqkT [2][512][256]
        int l = id8 - 49152; int n2 = l & 1023, k0 = (l >> 10) * 8;
        int ly = n2 >> 9, n = n2 & 511;
        const float* src = (n < 256) ? (Wq + ly * 65536 + n) : (Wk + ly * 65536 + (n - 256));
#pragma unroll
        for (int j = 0; j < 8; ++j) v[j] = src[(size_t)(k0 + j) * 256];
        dst = 393216 + (size_t)n2 * 256 + k0;
    } else if (id8 < 98304) {                   // wvT [512][256]
        int l = id8 - 81920; int n = l & 511, k0 = (l >> 9) * 8;
        const float* src = Wv + (n >> 8) * 65536 + (n & 255);
#pragma unroll
        for (int j = 0; j < 8; ++j) v[j] = src[(size_t)(k0 + j) * 256];
        dst = 655360 + (size_t)n * 256 + k0;
    } else if (id8 < 114688) {                  // o1WT [256][512]
        int l = id8 - 98304; int n = l & 255, k0 = (l >> 8) * 8;
#pragma unroll
        for (int j = 0; j < 8; ++j) v[j] = o1W[(size_t)(k0 + j) * 256 + n];
        dst = 786432 + (size_t)n * 512 + k0;
    } else {                                    // o2WT [256][256]
        int l = id8 - 114688; int n = l & 255, k0 = (l >> 8) * 8;
#pragma unroll
        for (int j = 0; j < 8; ++j) v[j] = o2W[(size_t)(k0 + j) * 256 + n];
        dst = 917504 + (size_t)n * 256 + k0;
    }
    union { ushort u[8]; uint4 q; } pk;
#pragma unroll
    for (int j = 0; j < 8; ++j) pk.u[j] = bfu(v[j]);
    *reinterpret_cast<uint4*>(wb + dst) = pk.q;
}

// ---------------------------------------------------------------------------
// Embedding gather + concept average -> bf16. 4 tokens/block, float4 lanes.
// ---------------------------------------------------------------------------
__global__ __launch_bounds__(256) void embed_k(
    const int* __restrict__ pid, const int* __restrict__ cdat,
    const float* __restrict__ qe, const float* __restrict__ ce,
    __hip_bfloat16* __restrict__ qemb, __hip_bfloat16* __restrict__ cemb)
{
    int tkn = blockIdx.x * 4 + (threadIdx.x >> 6);
    int e4  = (threadIdx.x & 63) * 4;
    int p = pid[tkn];
    float4 q = *reinterpret_cast<const float4*>(qe + (size_t)p * E_ + e4);
    ushort4 qo; qo.x = bfu(q.x); qo.y = bfu(q.y); qo.z = bfu(q.z); qo.w = bfu(q.w);
    *reinterpret_cast<ushort4*>(qemb + (size_t)tkn * E_ + e4) = qo;
    const int* c = cdat + (size_t)tkn * R_;
    float4 s = make_float4(0.f, 0.f, 0.f, 0.f);
#pragma unroll
    for (int r = 0; r < R_; ++r) {
        float4 v = *reinterpret_cast<const float4*>(ce + (size_t)c[r] * E_ + e4);
        s.x += v.x; s.y += v.y; s.z += v.z; s.w += v.w;
    }
    ushort4 co; co.x = bfu(s.x * 0.25f); co.y = bfu(s.y * 0.25f);
    co.z = bfu(s.z * 0.25f); co.w = bfu(s.w * 0.25f);
    *reinterpret_cast<ushort4*>(cemb + (size_t)tkn * E_ + e4) = co;
}

// ---------------------------------------------------------------------------
// bf16 MFMA GEMM body (device fn). M=16384, block 64x128, 4 waves of 32x64.
// AMODE: 0 plain (stride K) | 1 concat [A0|A1] | 2 gated select
// EPI: 0 none | 1 relu | 2 sigmoid
// OMODE: 0 f32 [M][Nstride] | 1 QK attn split | 2 V^T split 2 layers
//        | 3 bf16 [M][256] | 4 merged query(bf16,n<256)+sim(f32 sigmoid,n>=256)
// ---------------------------------------------------------------------------
template<int AMODE, int EPI, int OMODE, int K, int NB>
__device__ __forceinline__ void gemm_body(
    const __hip_bfloat16* __restrict__ A0, const __hip_bfloat16* __restrict__ A1,
    const int* __restrict__ lbl,
    const __hip_bfloat16* __restrict__ BT,
    const float* __restrict__ bias, const float* __restrict__ bias2,
    void* __restrict__ C0, void* __restrict__ C1, int Nstride, int did)
{
    const int lane = threadIdx.x & 63, w = threadIdx.x >> 6;
    const int col = lane & 15, rg = lane >> 4;
    const int wr = w >> 1, wc = w & 1;
    int bm, bn;
    if (NB == 512) {
        int swz = (did & 7) * 128 + (did >> 3);
        bm = (swz >> 2) * 64; bn = (swz & 3) * 128;
    } else {
        int swz = (did & 7) * 64 + (did >> 3);
        bm = (swz >> 1) * 64; bn = (swz & 1) * 128;
    }
    const f32x4_t z4 = {0.f, 0.f, 0.f, 0.f};
    f32x4_t acc[2][4] = {{z4, z4, z4, z4}, {z4, z4, z4, z4}};
    const bf16x8_t z8 = {0, 0, 0, 0, 0, 0, 0, 0};

    int rowA[2];
    rowA[0] = bm + wr * 32 + col;
    rowA[1] = bm + wr * 32 + 16 + col;
    int lblv[2] = {0, 0};
    if (AMODE == 2) { lblv[0] = lbl[rowA[0]]; lblv[1] = lbl[rowA[1]]; }
    const int nb0 = bn + wc * 64;

    auto load_step = [&](int s, bf16x8_t (&af)[2], bf16x8_t (&bfr)[4]) {
        const int kk = s * 32 + 8 * rg;
#pragma unroll
        for (int mt = 0; mt < 2; ++mt) {
            if (AMODE == 0) {
                af[mt] = *reinterpret_cast<const bf16x8_t*>(A0 + (size_t)rowA[mt] * K + kk);
            } else if (AMODE == 1) {
                const __hip_bfloat16* p = (kk < 256) ? (A0 + (size_t)rowA[mt] * 256 + kk)
                                                     : (A1 + (size_t)rowA[mt] * 256 + (kk - 256));
                af[mt] = *reinterpret_cast<const bf16x8_t*>(p);
            } else {
                bf16x8_t a = *reinterpret_cast<const bf16x8_t*>(A0 + (size_t)rowA[mt] * 256 + (kk & 255));
                bool first = (kk < 256);
                af[mt] = ((lblv[mt] != 0) == first) ? a : z8;
            }
        }
#pragma unroll
        for (int nt = 0; nt < 4; ++nt)
            bfr[nt] = *reinterpret_cast<const bf16x8_t*>(BT + (size_t)(nb0 + nt * 16 + col) * K + kk);
    };

    constexpr int NS = K / 32;
    bf16x8_t afb[2][2], bfb[2][4];
    load_step(0, afb[0], bfb[0]);
#pragma unroll
    for (int s = 0; s < NS; ++s) {
        if (s + 1 < NS) load_step(s + 1, afb[(s + 1) & 1], bfb[(s + 1) & 1]);
#pragma unroll
        for (int mt = 0; mt < 2; ++mt)
#pragma unroll
        for (int nt = 0; nt < 4; ++nt)
            acc[mt][nt] = __builtin_amdgcn_mfma_f32_16x16x32_bf16(afb[s & 1][mt], bfb[s & 1][nt], acc[mt][nt], 0, 0, 0);
    }

#pragma unroll
    for (int mt = 0; mt < 2; ++mt)
#pragma unroll
    for (int nt = 0; nt < 4; ++nt) {
        const int n = nb0 + nt * 16 + col;
        const int mb = bm + wr * 32 + mt * 16 + 4 * rg;
        float bs = 0.f;
        if (OMODE == 4) bs = (n < 256 && bias) ? bias[n] : 0.f;
        else if (bias) bs = (NB == 512 && n >= 256) ? bias2[n - 256] : bias[n];
        float xv[4];
#pragma unroll
        for (int r = 0; r < 4; ++r) {
            float x = acc[mt][nt][r] + bs;
            if (EPI == 1) x = fmaxf(x, 0.f);
            else if (EPI == 2) x = 1.f / (1.f + expf(-x));
            if (OMODE == 4 && n >= 256) x = 1.f / (1.f + expf(-x));
            xv[r] = x;
        }
        if (OMODE == 0) {
            if (n < Nstride) {
                float* C = (float*)C0;
#pragma unroll
                for (int r = 0; r < 4; ++r)
                    C[(size_t)(mb + r) * Nstride + n] = xv[r];
            }
        } else if (OMODE == 3) {
            __hip_bfloat16* Cb = (__hip_bfloat16*)C0;
#pragma unroll
            for (int r = 0; r < 4; ++r)
                Cb[(size_t)(mb + r) * 256 + n] = f2bf(xv[r]);
        } else if (OMODE == 4) {
            if (n < 256) {
                __hip_bfloat16* Cb = (__hip_bfloat16*)C0;
#pragma unroll
                for (int r = 0; r < 4; ++r)
                    Cb[(size_t)(mb + r) * 256 + n] = f2bf(xv[r]);
            } else if (n - 256 < NUMC_) {
                float* S = (float*)C1;
#pragma unroll
                for (int r = 0; r < 4; ++r)
                    S[(size_t)(mb + r) * NUMC_ + (n - 256)] = xv[r];
            }
        } else if (OMODE == 1) {
            __hip_bfloat16* dst = (n < 256) ? (__hip_bfloat16*)C0 : (__hip_bfloat16*)C1;
            const int nn = n & 255, hh = nn >> 5, d = nn & 31;
#pragma unroll
            for (int r = 0; r < 4; ++r) {
                int m = mb + r;
                int bh = (m >> 9) * 8 + hh;
                dst[((size_t)bh * 512 + (m & 511)) * 32 + d] = f2bf(xv[r]);
            }
        } else {   // OMODE 2: V^T, two layers
            __hip_bfloat16* dst = (n < 256) ? (__hip_bfloat16*)C0 : (__hip_bfloat16*)C1;
            const int nn = n & 255, hh = nn >> 5, d = nn & 31;
            const int bh = (mb >> 9) * 8 + hh;
            ushort4 pk;
            pk.x = bfu(xv[0]); pk.y = bfu(xv[1]); pk.z = bfu(xv[2]); pk.w = bfu(xv[3]);
            *reinterpret_cast<ushort4*>(dst + ((size_t)bh * 32 + d) * 512 + (mb & 511)) = pk;
        }
    }
}

template<int AMODE, int EPI, int OMODE, int K, int NB>
__global__ __launch_bounds__(256) void gemm_bf_k(
    const __hip_bfloat16* __restrict__ A0, const __hip_bfloat16* __restrict__ A1,
    const int* __restrict__ lbl,
    const __hip_bfloat16* __restrict__ BT,
    const float* __restrict__ bias, const float* __restrict__ bias2,
    void* __restrict__ C0, void* __restrict__ C1, int Nstride)
{
    gemm_body<AMODE, EPI, OMODE, K, NB>(A0, A1, lbl, BT, bias, bias2, C0, C1,
                                        Nstride, blockIdx.y * gridDim.x + blockIdx.x);
}

// ---------------------------------------------------------------------------
// Fused independent projections: z=0 -> QK layer-0 (A=query), z=1 -> V both
// layers (A=inter). 2048 blocks co-resident (8/CU) instead of 2x1024 serial.
// (r13: measured 55 us vs ~88 us serial — kept.)
// ---------------------------------------------------------------------------
__global__ __launch_bounds__(256) void qkv0_k(
    const __hip_bfloat16* __restrict__ query, const __hip_bfloat16* __restrict__ inter,
    const __hip_bfloat16* __restrict__ wqkT, const __hip_bfloat16* __restrict__ wvT,
    const float* __restrict__ bq, const float* __restrict__ bk,
    const float* __restrict__ bv,
    __hip_bfloat16* __restrict__ qbuf, __hip_bfloat16* __restrict__ kbuf,
    __hip_bfloat16* __restrict__ v0, __hip_bfloat16* __restrict__ v1)
{
    int did = blockIdx.y * 4 + blockIdx.x;
    if (blockIdx.z == 0)
        gemm_body<0, 0, 1, 256, 512>(query, nullptr, nullptr, wqkT, bq, bk, qbuf, kbuf, 0, did);
    else
        gemm_body<0, 0, 2, 256, 512>(inter, nullptr, nullptr, wvT, bv, bv + 256, v0, v1, 0, did);
}

// ---------------------------------------------------------------------------
// Fused head: pred[m] = sigmoid(relu(relu([outp|query]@o1W+b1)@o2W+b2).w3+b3).
// Block = 64 rows (r12 version; 32-row split regressed). Stage1: K=512 GEMM
// -> h1 in LDS [64][264]ush. Stage2: K=256 GEMM + relu.w3 reduce -> sigmoid.
// ---------------------------------------------------------------------------
#define HST 264
__global__ __launch_bounds__(256) void head_k(
    const __hip_bfloat16* __restrict__ A0, const __hip_bfloat16* __restrict__ A1,
    const __hip_bfloat16* __restrict__ o1WT, const float* __restrict__ b1,
    const __hip_bfloat16* __restrict__ o2WT, const float* __restrict__ b2,
    const float* __restrict__ w3, const float* __restrict__ b3,
    float* __restrict__ pred)
{
    __shared__ __align__(16) ushort ldsH[64 * HST];   // 33792 B
    __shared__ float sl[2][64];
    const int lane = threadIdx.x & 63, w = threadIdx.x >> 6;
    const int col = lane & 15, rg = lane >> 4;
    const int wr = w >> 1, wc = w & 1;
    const int bm = blockIdx.x * 64;
    const int nb0 = wc * 128;
    const f32x4_t z4 = {0.f, 0.f, 0.f, 0.f};

    int rowA[2];
    rowA[0] = bm + wr * 32 + col;
    rowA[1] = bm + wr * 32 + 16 + col;

    // ---- stage 1: h1 = relu([outp|query] @ o1WT + b1), wave tile 32x128 ----
    {
        f32x4_t acc[2][8];
#pragma unroll
        for (int mt = 0; mt < 2; ++mt)
#pragma unroll
        for (int nt = 0; nt < 8; ++nt) acc[mt][nt] = z4;

        auto load1 = [&](int s, bf16x8_t (&af)[2], bf16x8_t (&bfr)[8]) {
            const int kk = s * 32 + 8 * rg;
#pragma unroll
            for (int mt = 0; mt < 2; ++mt) {
                const __hip_bfloat16* p = (kk < 256) ? (A0 + (size_t)rowA[mt] * 256 + kk)
                                                     : (A1 + (size_t)rowA[mt] * 256 + (kk - 256));
                af[mt] = *reinterpret_cast<const bf16x8_t*>(p);
            }
#pragma unroll
            for (int nt = 0; nt < 8; ++nt)
                bfr[nt] = *reinterpret_cast<const bf16x8_t*>(o1WT + (size_t)(nb0 + nt * 16 + col) * 512 + kk);
        };
        bf16x8_t afb[2][2], bfb[2][8];
        load1(0, afb[0], bfb[0]);
#pragma unroll
        for (int s = 0; s < 16; ++s) {
            if (s + 1 < 16) load1(s + 1, afb[(s + 1) & 1], bfb[(s + 1) & 1]);
#pragma unroll
            for (int mt = 0; mt < 2; ++mt)
#pragma unroll
            for (int nt = 0; nt < 8; ++nt)
                acc[mt][nt] = __builtin_amdgcn_mfma_f32_16x16x32_bf16(afb[s & 1][mt], bfb[s & 1][nt], acc[mt][nt], 0, 0, 0);
        }
#pragma unroll
        for (int mt = 0; mt < 2; ++mt)
#pragma unroll
        for (int nt = 0; nt < 8; ++nt) {
            const int n = nb0 + nt * 16 + col;
            const float bs = b1[n];
            const int rb = wr * 32 + mt * 16 + 4 * rg;
#pragma unroll
            for (int r = 0; r < 4; ++r)
                ldsH[(rb + r) * HST + n] = bfu(fmaxf(acc[mt][nt][r] + bs, 0.f));
        }
    }
    __syncthreads();

    // ---- stage 2: h2 = relu(h1 @ o2WT + b2); pr = h2 . w3 ----
    {
        f32x4_t acc[2][8];
#pragma unroll
        for (int mt = 0; mt < 2; ++mt)
#pragma unroll
        for (int nt = 0; nt < 8; ++nt) acc[mt][nt] = z4;

        auto load2 = [&](int s, bf16x8_t (&af)[2], bf16x8_t (&bfr)[8]) {
            const int kk = s * 32 + 8 * rg;
#pragma unroll
            for (int mt = 0; mt < 2; ++mt)
                af[mt] = *reinterpret_cast<const bf16x8_t*>(
                    &ldsH[(wr * 32 + mt * 16 + col) * HST + kk]);
#pragma unroll
            for (int nt = 0; nt < 8; ++nt)
                bfr[nt] = *reinterpret_cast<const bf16x8_t*>(o2WT + (size_t)(nb0 + nt * 16 + col) * 256 + kk);
        };
        bf16x8_t afb[2][2], bfb[2][8];
        load2(0, afb[0], bfb[0]);
#pragma unroll
        for (int s = 0; s < 8; ++s) {
            if (s + 1 < 8) load2(s + 1, afb[(s + 1) & 1], bfb[(s + 1) & 1]);
#pragma unroll
            for (int mt = 0; mt < 2; ++mt)
#pragma unroll
            for (int nt = 0; nt < 8; ++nt)
                acc[mt][nt] = __builtin_amdgcn_mfma_f32_16x16x32_bf16(afb[s & 1][mt], bfb[s & 1][nt], acc[mt][nt], 0, 0, 0);
        }

        float pr[2][4] = {};
#pragma unroll
        for (int mt = 0; mt < 2; ++mt)
#pragma unroll
        for (int nt = 0; nt < 8; ++nt) {
            const int n = nb0 + nt * 16 + col;
            float bs = b2[n], wv = w3[n];
#pragma unroll
            for (int r = 0; r < 4; ++r)
                pr[mt][r] += fmaxf(acc[mt][nt][r] + bs, 0.f) * wv;
        }
#pragma unroll
        for (int mt = 0; mt < 2; ++mt)
#pragma unroll
        for (int r = 0; r < 4; ++r) {
            float v = pr[mt][r];
            v += __shfl_xor(v, 1); v += __shfl_xor(v, 2);
            v += __shfl_xor(v, 4); v += __shfl_xor(v, 8);
            if (col == 0) sl[wc][wr * 32 + mt * 16 + 4 * rg + r] = v;
        }
    }
    __syncthreads();
    if (threadIdx.x < 64) {
        float s = sl[0][threadIdx.x] + sl[1][threadIdx.x] + b3[0];
        pred[bm + threadIdx.x] = 1.f / (1.f + expf(-s));
    }
}

// ---------------------------------------------------------------------------
// Relative attention, bf16 MFMA, no-max softmax. ONE WAVE per workgroup,
// BAND-PAIRED: block = bands (p, 15-p) executed sequentially -> every block
// does exactly 17 tiles (uniform load). Grid (256 bh, 8 pairs) = 2048 blocks.
// LDS 9216 B, no syncs. exp via raw v_exp_f32 (scale prefolded). (r10-12 best)
// ---------------------------------------------------------------------------
#define QPST 36
template<int ADDREL>
__global__ __launch_bounds__(64) void attn1w_k(
    const __hip_bfloat16* __restrict__ Qbf, const __hip_bfloat16* __restrict__ Kbf,
    const __hip_bfloat16* __restrict__ Vt,  const __hip_bfloat16* __restrict__ pkPad,
    const __hip_bfloat16* __restrict__ pvT, __hip_bfloat16* __restrict__ outp)
{
    __shared__ __align__(16) ushort ldsA[64 * QPST];   // QP_T [64][36] / Ps [32][32]
    __shared__ __align__(16) ushort ldsP[2304];        // Prs  [32][72]

    const int lane = threadIdx.x;
    const int col = lane & 15, rg = lane >> 4;
    const int bh = blockIdx.x, b = bh >> 3, h = bh & 7;
    const int p = blockIdx.y;                  // pair index 0..7

    const __hip_bfloat16* Qb = Qbf + (size_t)bh * 512 * 32;
    const __hip_bfloat16* Kb = Kbf + (size_t)bh * 512 * 32;
    const __hip_bfloat16* Vb = Vt  + (size_t)bh * 32 * 512;

    const f32x4_t z4 = {0.f, 0.f, 0.f, 0.f};
    const float rscale2 = 0.17677669529663687f * 1.4426950408889634f;

    for (int ph = 0; ph < 2; ++ph) {
        const int band = ph ? p : (15 - p);    // long band first
        const int i0 = band * 32;
        const int nT = band + 1;

        // zero Prs (window [ii,ii+31] per row is tile-invariant; rest must be 0)
        {
            uint4 zz = make_uint4(0u, 0u, 0u, 0u);
            uint4* pz = reinterpret_cast<uint4*>(ldsP);
#pragma unroll
            for (int t = 0; t < 5; ++t) {
                int idx = lane + 64 * t;
                if (idx < 288) pz[idx] = zz;
            }
        }

        bf16x8_t qf[2];
        qf[0] = *reinterpret_cast<const bf16x8_t*>(Qb + (size_t)(i0 + col) * 32 + 8 * rg);
        qf[1] = *reinterpret_cast<const bf16x8_t*>(Qb + (size_t)(i0 + 16 + col) * 32 + 8 * rg);

        f32x4_t o[2][2] = {{z4, z4}, {z4, z4}};
        float lrow[2][4] = {};

        for (int t = 0; t < nT; ++t) {
            const int j0 = t * 32;
            bf16x8_t kf0 = *reinterpret_cast<const bf16x8_t*>(Kb + (size_t)(j0 + col) * 32 + 8 * rg);
            bf16x8_t kf1 = *reinterpret_cast<const bf16x8_t*>(Kb + (size_t)(j0 + 16 + col) * 32 + 8 * rg);
            const int prow0 = i0 - j0 + 1;
            bf16x8_t pkf[4];
#pragma unroll
            for (int rt = 0; rt < 4; ++rt)
                pkf[rt] = *reinterpret_cast<const bf16x8_t*>(
                    pkPad + (size_t)(prow0 + rt * 16 + col) * 32 + 8 * rg);

            __builtin_amdgcn_s_setprio(1);
            f32x4_t sA[2][2];
            sA[0][0] = __builtin_amdgcn_mfma_f32_16x16x32_bf16(qf[0], kf0, z4, 0, 0, 0);
            sA[0][1] = __builtin_amdgcn_mfma_f32_16x16x32_bf16(qf[0], kf1, z4, 0, 0, 0);
            sA[1][0] = __builtin_amdgcn_mfma_f32_16x16x32_bf16(qf[1], kf0, z4, 0, 0, 0);
            sA[1][1] = __builtin_amdgcn_mfma_f32_16x16x32_bf16(qf[1], kf1, z4, 0, 0, 0);
            f32x4_t qp0[4], qp1[4];
#pragma unroll
            for (int rt = 0; rt < 4; ++rt) {
                qp0[rt] = __builtin_amdgcn_mfma_f32_16x16x32_bf16(qf[0], pkf[rt], z4, 0, 0, 0);
                qp1[rt] = __builtin_amdgcn_mfma_f32_16x16x32_bf16(qf[1], pkf[rt], z4, 0, 0, 0);
            }
            __builtin_amdgcn_s_setprio(0);

            // QP transposed store: ldsA[x][ii], x = local rel 0..63, stride QPST
#pragma unroll
            for (int rt = 0; rt < 4; ++rt) {
                int xo = (rt * 16 + col) * QPST;
                uint2 wv;
                wv.x = pk2bf(qp0[rt][0], qp0[rt][1]);
                wv.y = pk2bf(qp0[rt][2], qp0[rt][3]);
                *reinterpret_cast<uint2*>(&ldsA[xo + 4 * rg]) = wv;
                wv.x = pk2bf(qp1[rt][0], qp1[rt][1]);
                wv.y = pk2bf(qp1[rt][2], qp1[rt][3]);
                *reinterpret_cast<uint2*>(&ldsA[xo + 16 + 4 * rg]) = wv;
            }

            // scores: gather QP diagonal, exp2 (scale prefolded), row sums
            const bool diag = (j0 == i0);
            float ev[2][2][4];
#pragma unroll
            for (int mt = 0; mt < 2; ++mt)
#pragma unroll
            for (int r = 0; r < 4; ++r) {
                const int ii = mt * 16 + 4 * rg + r;
#pragma unroll
                for (int nt = 0; nt < 2; ++nt) {
                    const int jj = nt * 16 + col;
                    float qpv = bf2f(ldsA[(ii - jj + 31) * QPST + ii]);
                    float sc = (sA[mt][nt][r] + qpv) * rscale2;
                    float e = __builtin_amdgcn_exp2f(sc);
                    if (diag && jj >= ii) e = 0.f;
                    ev[mt][nt][r] = e;
                }
                lrow[mt][r] += ev[mt][0][r] + ev[mt][1][r];
            }

            // P stores: dense swizzled Ps (reuses ldsA) + scattered Prs
#pragma unroll
            for (int mt = 0; mt < 2; ++mt)
#pragma unroll
            for (int nt = 0; nt < 2; ++nt)
#pragma unroll
            for (int r = 0; r < 4; ++r) {
                const int ii = mt * 16 + 4 * rg + r;
                const int jj = nt * 16 + col;
                ushort pe = bfu(ev[mt][nt][r]);
                ldsA[ii * 32 + (jj ^ ((ii & 3) << 3))] = pe;
                ldsP[ii * 72 + (ii - jj + 31)] = pe;
            }

            // O += P V  +  Pr posv
            bf16x8_t pa0 = *reinterpret_cast<const bf16x8_t*>(&ldsA[col * 32 + (8 * rg ^ ((col & 3) << 3))]);
            bf16x8_t pa1 = *reinterpret_cast<const bf16x8_t*>(&ldsA[(16 + col) * 32 + (8 * rg ^ ((col & 3) << 3))]);
            bf16x8_t vf0 = *reinterpret_cast<const bf16x8_t*>(Vb + (size_t)col * 512 + j0 + 8 * rg);
            bf16x8_t vf1 = *reinterpret_cast<const bf16x8_t*>(Vb + (size_t)(16 + col) * 512 + j0 + 8 * rg);
            bf16x8_t pr0[2], pr1[2], pv0[2], pv1[2];
#pragma unroll
            for (int ks = 0; ks < 2; ++ks) {
                pr0[ks] = *reinterpret_cast<const bf16x8_t*>(&ldsP[col * 72 + ks * 32 + 8 * rg]);
                pr1[ks] = *reinterpret_cast<const bf16x8_t*>(&ldsP[(16 + col) * 72 + ks * 32 + 8 * rg]);
                const __hip_bfloat16* pvb = pvT + (i0 - j0) + ks * 32 + 8 * rg;
                pv0[ks] = *reinterpret_cast<const bf16x8_t*>(pvb + (size_t)col * 576);
                pv1[ks] = *reinterpret_cast<const bf16x8_t*>(pvb + (size_t)(16 + col) * 576);
            }
            __builtin_amdgcn_s_setprio(1);
            o[0][0] = __builtin_amdgcn_mfma_f32_16x16x32_bf16(pa0, vf0, o[0][0], 0, 0, 0);
            o[0][1] = __builtin_amdgcn_mfma_f32_16x16x32_bf16(pa0, vf1, o[0][1], 0, 0, 0);
            o[1][0] = __builtin_amdgcn_mfma_f32_16x16x32_bf16(pa1, vf0, o[1][0], 0, 0, 0);
            o[1][1] = __builtin_amdgcn_mfma_f32_16x16x32_bf16(pa1, vf1, o[1][1], 0, 0, 0);
#pragma unroll
            for (int ks = 0; ks < 2; ++ks) {
                o[0][0] = __builtin_amdgcn_mfma_f32_16x16x32_bf16(pr0[ks], pv0[ks], o[0][0], 0, 0, 0);
                o[0][1] = __builtin_amdgcn_mfma_f32_16x16x32_bf16(pr0[ks], pv1[ks], o[0][1], 0, 0, 0);
                o[1][0] = __builtin_amdgcn_mfma_f32_16x16x32_bf16(pr1[ks], pv0[ks], o[1][0], 0, 0, 0);
                o[1][1] = __builtin_amdgcn_mfma_f32_16x16x32_bf16(pr1[ks], pv1[ks], o[1][1], 0, 0, 0);
            }
            __builtin_amdgcn_s_setprio(0);
        }

        // epilogue: reduce row sums, divide, (fused add-relu), bf16 store
#pragma unroll
        for (int mt = 0; mt < 2; ++mt)
#pragma unroll
        for (int r = 0; r < 4; ++r) {
            float ls = lrow[mt][r];
            ls += __shfl_xor(ls, 1); ls += __shfl_xor(ls, 2);
            ls += __shfl_xor(ls, 4); ls += __shfl_xor(ls, 8);
            const int i = i0 + mt * 16 + 4 * rg + r;
            float inv = (i == 0) ? 0.f : 1.0f / ls;
            __hip_bfloat16* orow = outp + (size_t)(b * 512 + i) * 256 + h * 32;
            float v0 = o[mt][0][r] * inv;
            float v1 = o[mt][1][r] * inv;
            if (ADDREL) {
                v0 = bf2f(*(ushort*)&orow[col])      + fmaxf(v0, 0.f);
                v1 = bf2f(*(ushort*)&orow[16 + col]) + fmaxf(v1, 0.f);
            }
            orow[col]      = f2bf(v0);
            orow[16 + col] = f2bf(v1);
        }
    }
}

// ---------------------------------------------------------------------------
extern "C" void kernel_launch(void* const* d_in, const int* in_sizes, int n_in,
                              void* d_out, int out_size, void* d_ws, size_t ws_size,
                              hipStream_t stream)
{
    const int*   pid        = (const int*)d_in[0];
    const int*   cdat       = (const int*)d_in[1];
    const int*   target     = (const int*)d_in[2];
    const float* que_emb    = (const float*)d_in[3];
    const float* concept_emb= (const float*)d_in[4];
    const float* posk       = (const float*)d_in[5];
    const float* posv       = (const float*)d_in[6];
    const float* qcW        = (const float*)d_in[7];
    const float* qcb        = (const float*)d_in[8];
    const float* linW       = (const float*)d_in[9];
    const float* linb       = (const float*)d_in[10];
    const float* Wq         = (const float*)d_in[11];
    const float* bq         = (const float*)d_in[12];
    const float* Wk         = (const float*)d_in[13];
    const float* bk         = (const float*)d_in[14];
    const float* Wv         = (const float*)d_in[15];
    const float* bv         = (const float*)d_in[16];
    const float* o1W        = (const float*)d_in[17];
    const float* o1b        = (const float*)d_in[18];
    const float* o2W        = (const float*)d_in[19];
    const float* o2b        = (const float*)d_in[20];
    const float* o3W        = (const float*)d_in[21];
    const float* o3b        = (const float*)d_in[22];

    float* out  = (float*)d_out;
    float* pred = out;                       // [B,S]
    float* sim  = out + MTOK;                // [B,S,200]

    __hip_bfloat16* wsb = (__hip_bfloat16*)d_ws;
    const size_t HB = (size_t)MTOK * E_;     // 4 Mi bf16 elems = 8 MB
    __hip_bfloat16* qemb  = wsb + 0 * HB;
    __hip_bfloat16* cemb  = wsb + 1 * HB;
    __hip_bfloat16* query = wsb + 2 * HB;
    __hip_bfloat16* inter = wsb + 3 * HB;
    __hip_bfloat16* qbuf  = wsb + 4 * HB;
    __hip_bfloat16* kbuf  = wsb + 5 * HB;
    __hip_bfloat16* v0    = wsb + 6 * HB;
    __hip_bfloat16* v1    = wsb + 7 * HB;
    __hip_bfloat16* outp  = wsb + 8 * HB;
    __hip_bfloat16* wb    = wsb + 9 * HB;    // 983040 weights + pads
    __hip_bfloat16* qcCe  = wb;              // [512][512] (qcWT ; ceT padded)
    __hip_bfloat16* linWT = wb + 262144;
    __hip_bfloat16* wqkT  = wb + 393216;     // [2][512][256]
    __hip_bfloat16* wvT   = wb + 655360;     // [512][256]
    __hip_bfloat16* o1WT  = wb + 786432;
    __hip_bfloat16* o2WT  = wb + 917504;
    __hip_bfloat16* pkPad = wb + 983040;     // 576*32
    __hip_bfloat16* pvT   = pkPad + 18432;   // 32*576

    dim3 blk(256);
    dim3 g256(2, 256);           // NB=256 GEMMs (512 blocks, 64x128 tiles)
    dim3 g512(4, 256);           // NB=512 GEMMs (1024 blocks)
    dim3 gqkv(4, 256, 2);        // fused QK0+V (2048 blocks)
    dim3 gattn(B_ * H_, 8);      // (bh, band pair) — one wave, 17 tiles each
    dim3 blk64(64);

    wcvt_k<<<552, blk, 0, stream>>>(qcW, linW, Wq, Wk, Wv, o1W, o2W, concept_emb,
                                    posk, posv, wb, pkPad, pvT);
    embed_k<<<MTOK / 4, blk, 0, stream>>>(pid, cdat, que_emb, concept_emb, qemb, cemb);

    // merged: query (n<256) = [qemb|cemb]@qcW+qcb ; sim (n>=256) = sigmoid(qemb@ce^T)
    gemm_bf_k<1, 0, 4, 512, 512><<<g512, blk, 0, stream>>>(qemb, cemb, nullptr, qcCe, qcb, nullptr, query, sim, 0);
    // inter = relu(gated(query) @ lin_W + lin_b)         -> bf16 [M][256]
    gemm_bf_k<2, 1, 3, 512, 256><<<g256, blk, 0, stream>>>(query, nullptr, target, linWT, linb, nullptr, inter, nullptr, 256);

    // fused independent projections: QK layer-0 + V both layers
    qkv0_k<<<gqkv, blk, 0, stream>>>(query, inter, wqkT, wvT, bq, bk, bv,
                                     qbuf, kbuf, v0, v1);
    attn1w_k<0><<<gattn, blk64, 0, stream>>>(qbuf, kbuf, v0, pkPad, pvT, outp);

    // ---- layer 1: q,k from outp; fused outp += relu(res) ----
    gemm_bf_k<0, 0, 1, 256, 512><<<g512, blk, 0, stream>>>(outp, nullptr, nullptr, wqkT + 131072, bq + 256, bk + 256, qbuf, kbuf, 0);
    attn1w_k<1><<<gattn, blk64, 0, stream>>>(qbuf, kbuf, v1, pkPad, pvT, outp);

    // fused head: o1 -> o2 -> o3 -> sigmoid (r12 64-row version)
    head_k<<<256, blk, 0, stream>>>(outp, query, o1WT, o1b, o2WT, o2b, o3W, o3b, pred);
}